// Round 11
// baseline (316.254 us; speedup 1.0000x reference)
//
#include <hip/hip_runtime.h>

#define DD 768
#define NCH 96
#define TPB 768        // 12 waves per block
#define NW 12
#define LPW 8          // labels per wave (12*8 = 96)
#define TROWS 32       // rows per tile
#define MBLK 256       // main grid
#define FTH 768        // finish threads

typedef unsigned int u32;

// dynamic LDS: rows f32[32][768] + rstd[32] + rmu[32] + lab[32]
#define LDS_BYTES (TROWS * DD * 4 + TROWS * 4 * 3)

__device__ __forceinline__ float wave_reduce_sum(float v) {
#pragma unroll
  for (int m = 32; m >= 1; m >>= 1) v += __shfl_xor(v, m, 64);
  return v;
}
__device__ __forceinline__ u32 bf2(float a, float b) {
  u32 ua = __float_as_uint(a); ua += 0x7fffu + ((ua >> 16) & 1u);
  u32 ub = __float_as_uint(b); ub += 0x7fffu + ((ub >> 16) & 1u);
  return (ua >> 16) | (ub & 0xffff0000u);
}
__device__ __forceinline__ float bflo(u32 u) { return __uint_as_float(u << 16); }
__device__ __forceinline__ float bfhi(u32 u) { return __uint_as_float(u & 0xffff0000u); }

// ---------- main: sequential x read; label-partitioned register accumulators ----------
__global__ void __launch_bounds__(TPB) k_main(
    const float* __restrict__ x, const int* __restrict__ tgt, int n, int tiles,
    u32* __restrict__ P16, float* __restrict__ Pm, float* __restrict__ Pc,
    float* __restrict__ gS, float* __restrict__ gpos, int* __restrict__ ctr) {
  extern __shared__ char smem[];
  float* rows   = (float*)smem;                       // [TROWS][DD]
  float* rstd_s = (float*)(smem + TROWS * DD * 4);    // [TROWS]
  float* rmu_s  = rstd_s + TROWS;                     // [TROWS]
  int*   lab_s  = (int*)(rmu_s + TROWS);              // [TROWS]

  int tid = threadIdx.x, w = tid >> 6, l = tid & 63, blk = blockIdx.x;
  if (blk == 0) {  // zero finish accumulators (consumed next dispatch)
    for (int i = tid; i < DD; i += TPB) gS[i] = 0.f;
    if (tid == 0) { gpos[0] = 0.f; ctr[0] = 0; }
  }

  float acc[LPW][12];
#pragma unroll
  for (int q = 0; q < LPW; ++q)
#pragma unroll
    for (int k = 0; k < 12; ++k) acc[q][k] = 0.f;
  float mc[LPW], ct[LPW];
#pragma unroll
  for (int q = 0; q < LPW; ++q) { mc[q] = 0.f; ct[q] = 0.f; }

  size_t base = (size_t)blk * ((size_t)tiles * TROWS);
  const float4* x4 = (const float4*)x;
  int rl[3] = { w, w + NW, w + 2 * NW };        // my rows in the tile
  bool hasr[3] = { true, true, (w + 2 * NW) < TROWS };

  // preamble: load tile 0 rows into pf
  float4 pf[3][3];
#pragma unroll
  for (int i = 0; i < 3; ++i) {
    size_t R = base + rl[i];
    if (R >= (size_t)n) R = (size_t)(n - 1);
    const float4* rp = x4 + R * 192;
    pf[i][0] = rp[l]; pf[i][1] = rp[64 + l]; pf[i][2] = rp[128 + l];
  }

  for (int t = 0; t < tiles; ++t) {
    // ---- Phase A: stats + LDS stage for my rows ----
#pragma unroll
    for (int i = 0; i < 3; ++i) {
      if (!hasr[i]) continue;
      size_t R = base + (size_t)t * TROWS + rl[i];
      bool valid = R < (size_t)n;
      float4 A = pf[i][0], B = pf[i][1], C = pf[i][2];
      float s = (A.x + A.y + A.z + A.w) + (B.x + B.y + B.z + B.w) +
                (C.x + C.y + C.z + C.w);
      float q = A.x*A.x + A.y*A.y + A.z*A.z + A.w*A.w +
                B.x*B.x + B.y*B.y + B.z*B.z + B.w*B.w +
                C.x*C.x + C.y*C.y + C.z*C.z + C.w*C.w;
      s = wave_reduce_sum(s);
      q = wave_reduce_sum(q);
      float mu = s * (1.f / DD);
      float rstd = rsqrtf(q * (1.f / DD) - mu * mu + 1e-5f);
      float* rp = rows + rl[i] * DD;
      *(float4*)&rp[4 * l] = A;
      *(float4*)&rp[256 + 4 * l] = B;
      *(float4*)&rp[512 + 4 * l] = C;
      int c = valid ? tgt[R] : -1;     // uniform addr -> broadcast
      if (l == 0) { rstd_s[rl[i]] = rstd; rmu_s[rl[i]] = rstd * mu; lab_s[rl[i]] = c; }
    }
    // ---- issue next tile's loads (in flight across Phase B) ----
    if (t + 1 < tiles) {
#pragma unroll
      for (int i = 0; i < 3; ++i) {
        size_t R = base + (size_t)(t + 1) * TROWS + rl[i];
        if (R >= (size_t)n) R = (size_t)(n - 1);
        const float4* rp = x4 + R * 192;
        pf[i][0] = rp[l]; pf[i][1] = rp[64 + l]; pf[i][2] = rp[128 + l];
      }
    }
    __syncthreads();
    // ---- Phase B: accumulate my labels from LDS tile ----
    for (int r = 0; r < TROWS; ++r) {
      int cl = __builtin_amdgcn_readfirstlane(lab_s[r]) - LPW * w;
      if ((unsigned)cl >= (unsigned)LPW) continue;
      float rs = rstd_s[r];
      float rm = rmu_s[r];
      const float* rp = rows + r * DD;
      float4 va = *(const float4*)&rp[4 * l];
      float4 vb = *(const float4*)&rp[256 + 4 * l];
      float4 vc = *(const float4*)&rp[512 + 4 * l];
#pragma unroll
      for (int q = 0; q < LPW; ++q) {
        if (q == cl) {
          acc[q][0] += rs * va.x; acc[q][1] += rs * va.y;
          acc[q][2] += rs * va.z; acc[q][3] += rs * va.w;
          acc[q][4] += rs * vb.x; acc[q][5] += rs * vb.y;
          acc[q][6] += rs * vb.z; acc[q][7] += rs * vb.w;
          acc[q][8] += rs * vc.x; acc[q][9] += rs * vc.y;
          acc[q][10] += rs * vc.z; acc[q][11] += rs * vc.w;
          mc[q] += rm; ct[q] += 1.f;
        }
      }
    }
    __syncthreads();
  }

  // ---- writeout: bf16 partials per (label, block) ----
  int nblk = gridDim.x;
#pragma unroll
  for (int q = 0; q < LPW; ++q) {
    int c = w * LPW + q;
    size_t bw = ((size_t)c * nblk + blk) * 384;
    uint2 u0 = make_uint2(bf2(acc[q][0], acc[q][1]), bf2(acc[q][2], acc[q][3]));
    uint2 u1 = make_uint2(bf2(acc[q][4], acc[q][5]), bf2(acc[q][6], acc[q][7]));
    uint2 u2 = make_uint2(bf2(acc[q][8], acc[q][9]), bf2(acc[q][10], acc[q][11]));
    *(uint2*)&P16[bw + 2 * l] = u0;
    *(uint2*)&P16[bw + 128 + 2 * l] = u1;
    *(uint2*)&P16[bw + 256 + 2 * l] = u2;
    if (l == 0) { Pm[c * nblk + blk] = mc[q]; Pc[c * nblk + blk] = ct[q]; }
  }
}

// ---------- finish: 96 blocks x 768 threads; partial reduce + tail math ----------
__global__ void __launch_bounds__(FTH) k_finish(
    const float* __restrict__ dic, const float* __restrict__ wln,
    const float* __restrict__ bln, const u32* __restrict__ P16,
    const float* __restrict__ Pm, const float* __restrict__ Pc, int nblk,
    float* __restrict__ gS, float* __restrict__ gpos, int* __restrict__ counter,
    float* __restrict__ out) {
  __shared__ float ps[2][384][2];
  __shared__ float mcsh, ncsh;
  __shared__ float red[12][3];
  __shared__ float fin[2];
  __shared__ int dsh;
  int c = blockIdx.x, tid = threadIdx.x, lane = tid & 63, wid = tid >> 6;
  if (tid == 0) { mcsh = 0.f; ncsh = 0.f; }
  __syncthreads();

  int h = tid / 384, word = tid % 384;
  float lo = 0.f, hi = 0.f;
  const u32* base = P16 + (size_t)c * nblk * 384;
  int b0 = h * (nblk / 2), b1 = b0 + nblk / 2;
  for (int b = b0; b < b1; ++b) {
    u32 u = base[(size_t)b * 384 + word];
    lo += bflo(u); hi += bfhi(u);
  }
  ps[h][word][0] = lo; ps[h][word][1] = hi;
  float mpart = (tid < nblk) ? Pm[c * nblk + tid] : 0.f;
  float npart = (tid < nblk) ? Pc[c * nblk + tid] : 0.f;
  mpart = wave_reduce_sum(mpart);
  npart = wave_reduce_sum(npart);
  if (lane == 0) { atomicAdd(&mcsh, mpart); atomicAdd(&ncsh, npart); }
  __syncthreads();

  int d = tid;                 // 0..767
  int wd = d >> 1, par = d & 1;
  float S1 = ps[0][wd][par] + ps[1][wd][par];
  float mcv = mcsh, nc = ncsh;
  float gg = dic[c * DD + d] + wln[d] * (S1 - mcv) + nc * bln[d];
  float inv = 1.f / (nc + 1.f);
  float u = dic[c * DD + d] + 0.1f * gg * inv;

  float pacc = wave_reduce_sum(gg * gg);
  float usum = wave_reduce_sum(u);
  float usq  = wave_reduce_sum(u * u);
  if (lane == 0) { red[wid][0] = pacc; red[wid][1] = usum; red[wid][2] = usq; }
  __syncthreads();
  if (tid == 0) {
    float tp = 0.f, ts = 0.f, tq = 0.f;
    for (int i = 0; i < 12; ++i) { tp += red[i][0]; ts += red[i][1]; tq += red[i][2]; }
    atomicAdd(gpos, tp);
    float mu = ts * (1.f / DD);
    fin[0] = mu;
    fin[1] = rsqrtf(tq * (1.f / DD) - mu * mu + 1e-5f);
  }
  __syncthreads();
  if (c >= 1) {
    float sacc = (u - fin[0]) * fin[1] * wln[d] + bln[d];
    atomicAdd(&gS[d], sacc);
  }

  __threadfence();
  __syncthreads();
  if (tid == 0) dsh = (atomicAdd(counter, 1) == NCH - 1) ? 1 : 0;
  __syncthreads();
  if (dsh) {
    __threadfence();
    float t = gS[d];
    float nv = wave_reduce_sum(t * t);
    if (lane == 0) red[wid][0] = nv;
    __syncthreads();
    if (tid == 0) {
      float tot = 0.f;
      for (int i = 0; i < 12; ++i) tot += red[i][0];
      out[0] = (tot - gpos[0]) * (1.f / DD);
    }
  }
}

extern "C" void kernel_launch(void* const* d_in, const int* in_sizes, int n_in,
                              void* d_out, int out_size, void* d_ws, size_t ws_size,
                              hipStream_t stream) {
  (void)n_in; (void)out_size; (void)ws_size;
  const float* x   = (const float*)d_in[0];
  const float* dic = (const float*)d_in[1];
  const float* w   = (const float*)d_in[2];
  const float* b   = (const float*)d_in[3];
  const int*   tgt = (const int*)d_in[4];
  float* out = (float*)d_out;
  int N = in_sizes[4];  // tokens (B*S = 131072)

  int nblk = MBLK;
  int tiles = (N + nblk * TROWS - 1) / (nblk * TROWS);  // 16

  char* ws = (char*)d_ws;
  float* gS   = (float*)(ws);                 // 3072 B
  float* gpos = (float*)(ws + 3072);
  int*   ctr  = (int*)(ws + 3076);
  float* Pm   = (float*)(ws + 4096);                              // 96*nblk*4
  float* Pc   = (float*)(ws + 4096 + (size_t)NCH * nblk * 4);     // 96*nblk*4
  u32*   P16  = (u32*)(ws + 4096 + 2 * (size_t)NCH * nblk * 4);   // 96*nblk*384*4

  hipFuncSetAttribute((const void*)k_main,
                      hipFuncAttributeMaxDynamicSharedMemorySize, LDS_BYTES);

  k_main<<<nblk, TPB, LDS_BYTES, stream>>>(x, tgt, N, tiles, P16, Pm, Pc, gS, gpos, ctr);
  k_finish<<<NCH, FTH, 0, stream>>>(dic, w, b, P16, Pm, Pc, nblk,
                                    gS, gpos, ctr, out);
}